// Round 5
// baseline (388.466 us; speedup 1.0000x reference)
//
#include <hip/hip_runtime.h>
#include <cstdint>
#include <cstddef>

// CRF forward NLL: B=512 chains, S=1024 steps, T=64 states.
// One wave per batch element. Exp-domain recurrence, quarter-split matvec:
//   lane l = (g = l>>2, c = l&3) owns state j = 4g+c = l.
//   Per step: lane reads A-quarter [16c,16c+16) from LDS (4x ds_read_b128),
//   computes P[r] = sum_{i in quarter} A[i]*E[i][4g+r] (32 pk-FMAs, E in VGPRs),
//   quad DPP butterfly (xor1,xor2) + cndmask-select -> s_l,
//   W_new[l] = s_l * exp(emit_l) * 2^-pend  (pend = prev step's lane0 exponent,
//   folded off-chain), ds_write_b32. Mk accumulates applied exponents exactly.
// No log/exp/max/readfirstlane on the serial chain.

#define S_ 1024
#define T_ 64

typedef float f32x2 __attribute__((ext_vector_type(2)));
typedef float f32x4 __attribute__((ext_vector_type(4)));

__device__ __forceinline__ float rl_f(float v, int lane) {
  return __int_as_float(__builtin_amdgcn_readlane(__float_as_int(v), lane));
}

template <int CTRL>
__device__ __forceinline__ float dppq(float v) {
  // quad_perm DPP: CTRL=0xB1 -> lane^1, CTRL=0x4E -> lane^2 (within quads)
  return __int_as_float(__builtin_amdgcn_update_dpp(
      0, __float_as_int(v), CTRL, 0xF, 0xF, true));
}

__launch_bounds__(64, 1)
__global__ void crf_scan(const float* __restrict__ feats,
                         const int* __restrict__ tags,
                         const int* __restrict__ mask,
                         const float* __restrict__ trans,
                         float* __restrict__ out) {
  const int b = blockIdx.x;
  const int lane = threadIdx.x;
  const int g = lane >> 2;   // group 0..15 (owns states 4g..4g+3)
  const int c = lane & 3;    // quad pos == A-quarter index

  __shared__ __align__(16) float Abuf[2][T_];
  __shared__ int tmeta[S_];

  const float LOG2E = 1.4426950408889634f;

  // ---- stage tags+mask into LDS as (tag | mask<<8), coalesced ----
  const int* tagb = tags + (size_t)b * S_;
  const int* mb = mask + (size_t)b * S_;
  #pragma unroll
  for (int t0 = 0; t0 < S_; t0 += 64) {
    int t = t0 + lane;
    tmeta[t] = (tagb[t] & 63) | (mb[t] != 0 ? 256 : 0);
  }

  // ---- E fragments: er2[r][p] = {E[16c+2p][4g+r], E[16c+2p+1][4g+r]} ----
  f32x2 er2[4][8];
  #pragma unroll
  for (int r = 0; r < 4; ++r) {
    #pragma unroll
    for (int p = 0; p < 8; ++p) {
      int i0 = 16 * c + 2 * p;
      int j = 4 * g + r;
      f32x2 e;
      e.x = exp2f(trans[(size_t)i0 * T_ + j] * LOG2E);
      e.y = exp2f(trans[(size_t)(i0 + 1) * T_ + j] * LOG2E);
      er2[r][p] = e;
    }
  }

  // ---- gold: precompute transition term lane-parallel (t = 1..1023) ----
  float gtr = 0.0f;
  #pragma unroll
  for (int u = 0; u < 16; ++u) {
    int t = lane * 16 + u + 1;
    if (t < S_) {
      int m1 = tmeta[t];
      if (m1 & 256) {
        int m0 = tmeta[t - 1];
        gtr += trans[(m0 & 255) * T_ + (m1 & 255)];
      }
    }
  }

  // ---- t = 0 init ----
  const float* fb = feats + (size_t)b * S_ * T_ + lane;
  float e0 = fb[0];                 // emit[b,0,lane] == alpha0[lane]
  float A0 = exp2f(e0 * LOG2E);
  Abuf[0][lane] = A0;
  float Aown = A0;
  int Mk = 0;                       // applied exponent sum (exact, uniform)
  int wb0 = __builtin_amdgcn_readfirstlane(__float_as_int(A0));
  int pend = (int)(((unsigned)wb0 >> 23) & 255) - 127;   // lane0 exponent
  float scale_pend = __int_as_float((127 - pend) << 23); // 2^-pend

  int tm0 = __builtin_amdgcn_readfirstlane(tmeta[0]);
  float gold = (tm0 & 256) ? rl_f(e0, tm0 & 255) : 0.0f;

  // ---- one scan step (t >= 1); rb compile-time after unroll ----
  auto stepf = [&](int rb, int tmt, float ecu, float eEu) {
    int tag = tmt & 255;
    int mk  = (tmt >> 8) & 1;
    float ce = eEu * scale_pend;   // off-chain: prev pend folded into emit

    // quarter read: A[16c .. 16c+16)
    const f32x4* Ab = (const f32x4*)&Abuf[rb][0];
    f32x4 Aq[4];
    #pragma unroll
    for (int r = 0; r < 4; ++r) Aq[r] = Ab[4 * c + r];

    // partials for this group's 4 states over own quarter (32 pk-FMAs)
    f32x2 P0 = {0.f, 0.f}, P1 = {0.f, 0.f}, P2 = {0.f, 0.f}, P3 = {0.f, 0.f};
    #pragma unroll
    for (int p = 0; p < 8; ++p) {
      f32x4 q = Aq[p >> 1];
      f32x2 av;
      av.x = (p & 1) ? q.z : q.x;  // compile-time after unroll
      av.y = (p & 1) ? q.w : q.y;
      P0 += av * er2[0][p];
      P1 += av * er2[1][p];
      P2 += av * er2[2][p];
      P3 += av * er2[3][p];
    }
    float p0 = P0.x + P0.y, p1 = P1.x + P1.y;
    float p2 = P2.x + P2.y, p3 = P3.x + P3.y;

    // quad butterfly: full sums for r=0..3 in every lane of the quad
    float q0 = p0 + dppq<0xB1>(p0);
    float q1 = p1 + dppq<0xB1>(p1);
    float q2 = p2 + dppq<0xB1>(p2);
    float q3 = p3 + dppq<0xB1>(p3);
    float r0 = q0 + dppq<0x4E>(q0);
    float r1 = q1 + dppq<0x4E>(q1);
    float r2 = q2 + dppq<0x4E>(q2);
    float r3 = q3 + dppq<0x4E>(q3);
    float s01 = (c & 1) ? r1 : r0;
    float s23 = (c & 1) ? r3 : r2;
    float s = (c & 2) ? s23 : s01;   // s == s_{lane}

    float An = s * ce;
    float Aw = mk ? An : Aown;
    Abuf[rb ^ 1][lane] = Aw;
    Aown = Aw;

    // off-chain bookkeeping
    Mk += mk ? pend : 0;             // pend was applied iff masked
    int wb = __builtin_amdgcn_readfirstlane(__float_as_int(Aw));
    pend = (int)(((unsigned)wb >> 23) & 255) - 127;
    scale_pend = __int_as_float((127 - pend) << 23);
    if (mk) gold += rl_f(ecu, tag);
  };

  // ---- prefetch first chunk of emits (t = 1..8) ----
  float epf[8];
  #pragma unroll
  for (int u = 0; u < 8; ++u) epf[u] = fb[(size_t)(1 + u) * T_];

  // ---- main scan: 127 branch-free chunks of 8 (t = 1..1016) ----
  for (int cc = 0; cc < 127; ++cc) {
    const int tbase = 1 + cc * 8;

    float ecur[8], eE[8];
    #pragma unroll
    for (int u = 0; u < 8; ++u) ecur[u] = epf[u];
    #pragma unroll
    for (int u = 0; u < 8; ++u) eE[u] = exp2f(ecur[u] * LOG2E);

    // chunk metadata: lanes 0..7 hold tmeta[tbase+0..7]; readlane per step
    int tmv = tmeta[tbase + (lane & 7)];

    // prefetch next chunk (branch-free OOB clamp; clamped value unused)
    #pragma unroll
    for (int u = 0; u < 8; ++u) {
      int t = tbase + 8 + u;
      int tc = t < S_ ? t : S_ - 1;
      epf[u] = fb[(size_t)tc * T_];
    }

    #pragma unroll
    for (int u = 0; u < 8; ++u) {
      int tmt = __builtin_amdgcn_readlane(tmv, u);
      stepf(u & 1, tmt, ecur[u], eE[u]);
    }
  }

  // ---- tail: t = 1017..1023 (7 steps; parity continues: 1016 % 2 == 0) ----
  {
    int tt = 1017 + (lane & 7);
    if (tt > 1023) tt = 1023;
    int tmv = tmeta[tt];
    float ecur[7], eE[7];
    #pragma unroll
    for (int u = 0; u < 7; ++u) {
      ecur[u] = epf[u];
      eE[u] = exp2f(ecur[u] * LOG2E);
    }
    #pragma unroll
    for (int u = 0; u < 7; ++u) {
      int tmt = __builtin_amdgcn_readlane(tmv, u);
      stepf(u & 1, tmt, ecur[u], eE[u]);
    }
  }

  // ---- norm = Mk*ln2 + ln(sum_j W[j]); out = norm - gold ----
  float ssum = Aown;
  float gsum = gtr;
  #pragma unroll
  for (int k = 32; k >= 1; k >>= 1) {
    ssum += __shfl_xor(ssum, k, 64);
    gsum += __shfl_xor(gsum, k, 64);
  }
  double norm = ((double)Mk + (double)log2f(ssum)) * 0.6931471805599453;
  double goldall = (double)gold + (double)gsum;
  if (lane == 0) out[b] = (float)(norm - goldall);
}

extern "C" void kernel_launch(void* const* d_in, const int* in_sizes, int n_in,
                              void* d_out, int out_size, void* d_ws, size_t ws_size,
                              hipStream_t stream) {
  const float* feats = (const float*)d_in[0];
  const int* tags = (const int*)d_in[1];
  const int* mask = (const int*)d_in[2];
  const float* trans = (const float*)d_in[3];
  float* out = (float*)d_out;

  int Bn = in_sizes[0] / (S_ * T_);  // 512
  hipLaunchKernelGGL(crf_scan, dim3(Bn), dim3(64), 0, stream,
                     feats, tags, mask, trans, out);
}

// Round 6
// 366.108 us; speedup vs baseline: 1.0611x; 1.0611x over previous
//
#include <hip/hip_runtime.h>
#include <cstdint>
#include <cstddef>

// CRF forward NLL: B=512 chains, S=1024 steps, T=64 states.
// One wave per batch element. Exp-domain recurrence, quarter-split matvec:
//   lane l = (g = l>>2, c = l&3) owns state j = 4g+c = l.
//   Per step: lane reads A-quarter [16c,16c+16) from LDS (4x ds_read_b128),
//   computes P[r] = sum_{i in quarter} A[i]*E[i][4g+r] (32 pk-FMAs, E in VGPRs),
//   quad DPP butterfly (xor1,xor2) + select -> s_l,
//   W_new[l] = s_l * exp(emit_l) * 2^-pend (pend = prev lane0 exponent, off-chain),
//   ds_write_b32. Mk accumulates applied exponents exactly.
// Round-5 postmortem: lambda-based step body was NOT fully inlined -> er2
// captured by reference went to scratch (VGPR_Count=60 < 64 needed), kernel
// became L2/scratch-bound (~33 TB/s, VALUBusy 22%). This version uses macros
// + hand-unrolled named scalars ONLY -- nothing can legally spill.

#define S_ 1024
#define T_ 64

typedef float f32x2 __attribute__((ext_vector_type(2)));
typedef float f32x4 __attribute__((ext_vector_type(4)));

__device__ __forceinline__ float rl_f(float v, int lane) {
  return __int_as_float(__builtin_amdgcn_readlane(__float_as_int(v), lane));
}

template <int CTRL>
__device__ __forceinline__ float dppq(float v) {
  // quad_perm DPP: CTRL=0xB1 -> lane^1, CTRL=0x4E -> lane^2 (within quads)
  return __int_as_float(__builtin_amdgcn_update_dpp(
      0, __float_as_int(v), CTRL, 0xF, 0xF, true));
}

// one pk-FMA group: A-pair (AVX,AVY) times E columns for this group's 4 states
#define FMA4(AVX, AVY, P) { \
  f32x2 av_; av_.x = (AVX); av_.y = (AVY); \
  P0_ += av_ * er2[0][P]; P1_ += av_ * er2[1][P]; \
  P2_ += av_ * er2[2][P]; P3_ += av_ * er2[3][P]; }

// one scan step (t>=1). RB = LDS buffer parity (compile-time constant).
#define STEPF(RB, TMT, ECU, EEU) { \
  const int tmt_ = (TMT); \
  const int tag_ = tmt_ & 255; \
  const int mk_  = (tmt_ >> 8) & 1; \
  const float ce_ = (EEU) * scale_pend; \
  const f32x4* Ab_ = (const f32x4*)&Abuf[(RB)][0]; \
  const f32x4 q0_ = Ab_[4 * c + 0]; \
  const f32x4 q1_ = Ab_[4 * c + 1]; \
  const f32x4 q2_ = Ab_[4 * c + 2]; \
  const f32x4 q3_ = Ab_[4 * c + 3]; \
  f32x2 P0_ = {0.f, 0.f}, P1_ = {0.f, 0.f}, P2_ = {0.f, 0.f}, P3_ = {0.f, 0.f}; \
  FMA4(q0_.x, q0_.y, 0); FMA4(q0_.z, q0_.w, 1); \
  FMA4(q1_.x, q1_.y, 2); FMA4(q1_.z, q1_.w, 3); \
  FMA4(q2_.x, q2_.y, 4); FMA4(q2_.z, q2_.w, 5); \
  FMA4(q3_.x, q3_.y, 6); FMA4(q3_.z, q3_.w, 7); \
  float p0_ = P0_.x + P0_.y, p1_ = P1_.x + P1_.y; \
  float p2_ = P2_.x + P2_.y, p3_ = P3_.x + P3_.y; \
  float qq0_ = p0_ + dppq<0xB1>(p0_); \
  float qq1_ = p1_ + dppq<0xB1>(p1_); \
  float qq2_ = p2_ + dppq<0xB1>(p2_); \
  float qq3_ = p3_ + dppq<0xB1>(p3_); \
  float r0_ = qq0_ + dppq<0x4E>(qq0_); \
  float r1_ = qq1_ + dppq<0x4E>(qq1_); \
  float r2_ = qq2_ + dppq<0x4E>(qq2_); \
  float r3_ = qq3_ + dppq<0x4E>(qq3_); \
  float s01_ = (c & 1) ? r1_ : r0_; \
  float s23_ = (c & 1) ? r3_ : r2_; \
  float s_ = (c & 2) ? s23_ : s01_; \
  float An_ = s_ * ce_; \
  float Aw_ = mk_ ? An_ : Aown; \
  Abuf[(RB) ^ 1][lane] = Aw_; \
  Aown = Aw_; \
  Mk += mk_ ? pend : 0; \
  int wb_ = __builtin_amdgcn_readfirstlane(__float_as_int(Aw_)); \
  pend = (int)(((unsigned)wb_ >> 23) & 255) - 127; \
  scale_pend = __int_as_float((127 - pend) << 23); \
  if (mk_) gold += rl_f((ECU), tag_); \
}

#define RL(V, U) __builtin_amdgcn_readlane((V), (U))

__launch_bounds__(64, 1)
__global__ void crf_scan(const float* __restrict__ feats,
                         const int* __restrict__ tags,
                         const int* __restrict__ mask,
                         const float* __restrict__ trans,
                         float* __restrict__ out) {
  const int b = blockIdx.x;
  const int lane = threadIdx.x;
  const int g = lane >> 2;   // group 0..15 (owns states 4g..4g+3)
  const int c = lane & 3;    // quad pos == A-quarter index

  __shared__ __align__(16) float Abuf[2][T_];
  __shared__ int tmeta[S_];

  const float LOG2E = 1.4426950408889634f;

  // ---- stage tags+mask into LDS as (tag | mask<<8), coalesced ----
  const int* tagb = tags + (size_t)b * S_;
  const int* mb = mask + (size_t)b * S_;
  #pragma unroll
  for (int t0 = 0; t0 < S_; t0 += 64) {
    int t = t0 + lane;
    tmeta[t] = (tagb[t] & 63) | (mb[t] != 0 ? 256 : 0);
  }

  // ---- E fragments: er2[r][p] = {E[16c+2p][4g+r], E[16c+2p+1][4g+r]} ----
  f32x2 er2[4][8];
  #pragma unroll
  for (int r = 0; r < 4; ++r) {
    #pragma unroll
    for (int p = 0; p < 8; ++p) {
      int i0 = 16 * c + 2 * p;
      int j = 4 * g + r;
      f32x2 e;
      e.x = exp2f(trans[(size_t)i0 * T_ + j] * LOG2E);
      e.y = exp2f(trans[(size_t)(i0 + 1) * T_ + j] * LOG2E);
      er2[r][p] = e;
    }
  }

  // ---- gold: precompute transition term lane-parallel (t = 1..1023) ----
  float gtr = 0.0f;
  #pragma unroll
  for (int u = 0; u < 16; ++u) {
    int t = lane * 16 + u + 1;
    if (t < S_) {
      int m1 = tmeta[t];
      if (m1 & 256) {
        int m0 = tmeta[t - 1];
        gtr += trans[(m0 & 255) * T_ + (m1 & 255)];
      }
    }
  }

  // ---- t = 0 init ----
  const float* fb = feats + (size_t)b * S_ * T_ + lane;
  float e0i = fb[0];                // emit[b,0,lane] == alpha0[lane]
  float A0 = exp2f(e0i * LOG2E);
  Abuf[0][lane] = A0;
  float Aown = A0;
  int Mk = 0;                       // applied exponent sum (exact, uniform)
  int wb0 = __builtin_amdgcn_readfirstlane(__float_as_int(A0));
  int pend = (int)(((unsigned)wb0 >> 23) & 255) - 127;   // lane0 exponent
  float scale_pend = __int_as_float((127 - pend) << 23); // 2^-pend

  int tm0 = __builtin_amdgcn_readfirstlane(tmeta[0]);
  float gold = (tm0 & 256) ? rl_f(e0i, tm0 & 255) : 0.0f;

  // ---- prefetch first chunk of emits (t = 1..8), named scalars only ----
  float epf0 = fb[(size_t)1 * T_], epf1 = fb[(size_t)2 * T_];
  float epf2 = fb[(size_t)3 * T_], epf3 = fb[(size_t)4 * T_];
  float epf4 = fb[(size_t)5 * T_], epf5 = fb[(size_t)6 * T_];
  float epf6 = fb[(size_t)7 * T_], epf7 = fb[(size_t)8 * T_];

  // ---- main scan: 127 chunks of 8 steps (t = 1..1016) ----
  for (int cc = 0; cc < 127; ++cc) {
    const int tbase = 1 + cc * 8;

    float ec0 = epf0, ec1 = epf1, ec2 = epf2, ec3 = epf3;
    float ec4 = epf4, ec5 = epf5, ec6 = epf6, ec7 = epf7;
    float ex0 = exp2f(ec0 * LOG2E), ex1 = exp2f(ec1 * LOG2E);
    float ex2 = exp2f(ec2 * LOG2E), ex3 = exp2f(ec3 * LOG2E);
    float ex4 = exp2f(ec4 * LOG2E), ex5 = exp2f(ec5 * LOG2E);
    float ex6 = exp2f(ec6 * LOG2E), ex7 = exp2f(ec7 * LOG2E);

    // chunk metadata: lanes 0..7 hold tmeta[tbase+0..7]
    int tmv = tmeta[tbase + (lane & 7)];

    // prefetch next chunk (tbase+8 .. tbase+15; only +15 can be OOB)
    {
      const float* fpn = fb + (size_t)(tbase + 8) * T_;
      epf0 = fpn[0 * T_]; epf1 = fpn[1 * T_];
      epf2 = fpn[2 * T_]; epf3 = fpn[3 * T_];
      epf4 = fpn[4 * T_]; epf5 = fpn[5 * T_];
      epf6 = fpn[6 * T_];
      int t7 = tbase + 15;
      epf7 = fb[(size_t)(t7 < S_ ? t7 : S_ - 1) * T_];
    }

    STEPF(0, RL(tmv, 0), ec0, ex0);
    STEPF(1, RL(tmv, 1), ec1, ex1);
    STEPF(0, RL(tmv, 2), ec2, ex2);
    STEPF(1, RL(tmv, 3), ec3, ex3);
    STEPF(0, RL(tmv, 4), ec4, ex4);
    STEPF(1, RL(tmv, 5), ec5, ex5);
    STEPF(0, RL(tmv, 6), ec6, ex6);
    STEPF(1, RL(tmv, 7), ec7, ex7);
  }

  // ---- tail: t = 1017..1023 (7 steps; A is in buffer 0 at entry) ----
  {
    int tt = 1017 + (lane & 7);
    if (tt > 1023) tt = 1023;
    int tmv = tmeta[tt];
    float ex0 = exp2f(epf0 * LOG2E), ex1 = exp2f(epf1 * LOG2E);
    float ex2 = exp2f(epf2 * LOG2E), ex3 = exp2f(epf3 * LOG2E);
    float ex4 = exp2f(epf4 * LOG2E), ex5 = exp2f(epf5 * LOG2E);
    float ex6 = exp2f(epf6 * LOG2E);

    STEPF(0, RL(tmv, 0), epf0, ex0);
    STEPF(1, RL(tmv, 1), epf1, ex1);
    STEPF(0, RL(tmv, 2), epf2, ex2);
    STEPF(1, RL(tmv, 3), epf3, ex3);
    STEPF(0, RL(tmv, 4), epf4, ex4);
    STEPF(1, RL(tmv, 5), epf5, ex5);
    STEPF(0, RL(tmv, 6), epf6, ex6);
  }

  // ---- norm = Mk*ln2 + ln(sum_j W[j]); out = norm - gold ----
  float ssum = Aown;
  float gsum = gtr;
  #pragma unroll
  for (int k = 32; k >= 1; k >>= 1) {
    ssum += __shfl_xor(ssum, k, 64);
    gsum += __shfl_xor(gsum, k, 64);
  }
  double norm = ((double)Mk + (double)log2f(ssum)) * 0.6931471805599453;
  double goldall = (double)gold + (double)gsum;
  if (lane == 0) out[b] = (float)(norm - goldall);
}

extern "C" void kernel_launch(void* const* d_in, const int* in_sizes, int n_in,
                              void* d_out, int out_size, void* d_ws, size_t ws_size,
                              hipStream_t stream) {
  const float* feats = (const float*)d_in[0];
  const int* tags = (const int*)d_in[1];
  const int* mask = (const int*)d_in[2];
  const float* trans = (const float*)d_in[3];
  float* out = (float*)d_out;

  int Bn = in_sizes[0] / (S_ * T_);  // 512
  hipLaunchKernelGGL(crf_scan, dim3(Bn), dim3(64), 0, stream,
                     feats, tags, mask, trans, out);
}

// Round 9
// 362.133 us; speedup vs baseline: 1.0727x; 1.0110x over previous
//
#include <hip/hip_runtime.h>
#include <cstdint>
#include <cstddef>

// CRF forward NLL: B=512 chains, S=1024 steps, T=64 states.
// One wave per batch element. Exp-domain recurrence, quarter-split matvec:
//   lane l = (g = l>>2, c = l&3) owns state j = 4g+c = l.
//   Per step: lane reads A-quarter [16c,16c+16) from LDS (4x ds_read_b128),
//   computes P[r] = sum_{i in quarter} A[i]*E[i][4g+r] (32 pk-FMAs, E in VGPRs),
//   quad DPP butterfly (xor1,xor2) + select -> s_l,
//   W_new[l] = s_l * exp(emit_l) * 2^-pend (pend = prev lane0 exponent, off-chain),
//   ds_write_b32. Mk accumulates applied exponents exactly.
// Round-6 postmortem (measured r5): VGPR_Count=60 -> allocator targets default
// occupancy and spills er2 (64 floats) to scratch; ~300 cy/step of stall
// matches scratch reloads. launch_bounds' 2nd arg only sets the MIN waves/EU
// (a floor), so here we set amdgpu_waves_per_eu(1,1): max=1 makes the full
// 512-VGPR file the pressure target. Grid = 512 single-wave blocks on 1024
// SIMDs, so >1 wave/EU was never reachable anyway.

#define S_ 1024
#define T_ 64

typedef float f32x2 __attribute__((ext_vector_type(2)));
typedef float f32x4 __attribute__((ext_vector_type(4)));

__device__ __forceinline__ float rl_f(float v, int lane) {
  return __int_as_float(__builtin_amdgcn_readlane(__float_as_int(v), lane));
}

template <int CTRL>
__device__ __forceinline__ float dppq(float v) {
  // quad_perm DPP: CTRL=0xB1 -> lane^1, CTRL=0x4E -> lane^2 (within quads)
  return __int_as_float(__builtin_amdgcn_update_dpp(
      0, __float_as_int(v), CTRL, 0xF, 0xF, true));
}

// one pk-FMA group: A-pair (AVX,AVY) times E columns for this group's 4 states
#define FMA4(AVX, AVY, P) { \
  f32x2 av_; av_.x = (AVX); av_.y = (AVY); \
  P0_ += av_ * er2[0][P]; P1_ += av_ * er2[1][P]; \
  P2_ += av_ * er2[2][P]; P3_ += av_ * er2[3][P]; }

// one scan step (t>=1). RB = LDS buffer parity (compile-time constant).
#define STEPF(RB, TMT, ECU, EEU) { \
  const int tmt_ = (TMT); \
  const int tag_ = tmt_ & 255; \
  const int mk_  = (tmt_ >> 8) & 1; \
  const float ce_ = (EEU) * scale_pend; \
  const f32x4* Ab_ = (const f32x4*)&Abuf[(RB)][0]; \
  const f32x4 q0_ = Ab_[4 * c + 0]; \
  const f32x4 q1_ = Ab_[4 * c + 1]; \
  const f32x4 q2_ = Ab_[4 * c + 2]; \
  const f32x4 q3_ = Ab_[4 * c + 3]; \
  f32x2 P0_ = {0.f, 0.f}, P1_ = {0.f, 0.f}, P2_ = {0.f, 0.f}, P3_ = {0.f, 0.f}; \
  FMA4(q0_.x, q0_.y, 0); FMA4(q0_.z, q0_.w, 1); \
  FMA4(q1_.x, q1_.y, 2); FMA4(q1_.z, q1_.w, 3); \
  FMA4(q2_.x, q2_.y, 4); FMA4(q2_.z, q2_.w, 5); \
  FMA4(q3_.x, q3_.y, 6); FMA4(q3_.z, q3_.w, 7); \
  float p0_ = P0_.x + P0_.y, p1_ = P1_.x + P1_.y; \
  float p2_ = P2_.x + P2_.y, p3_ = P3_.x + P3_.y; \
  float qq0_ = p0_ + dppq<0xB1>(p0_); \
  float qq1_ = p1_ + dppq<0xB1>(p1_); \
  float qq2_ = p2_ + dppq<0xB1>(p2_); \
  float qq3_ = p3_ + dppq<0xB1>(p3_); \
  float r0_ = qq0_ + dppq<0x4E>(qq0_); \
  float r1_ = qq1_ + dppq<0x4E>(qq1_); \
  float r2_ = qq2_ + dppq<0x4E>(qq2_); \
  float r3_ = qq3_ + dppq<0x4E>(qq3_); \
  float s01_ = (c & 1) ? r1_ : r0_; \
  float s23_ = (c & 1) ? r3_ : r2_; \
  float s_ = (c & 2) ? s23_ : s01_; \
  float An_ = s_ * ce_; \
  float Aw_ = mk_ ? An_ : Aown; \
  Abuf[(RB) ^ 1][lane] = Aw_; \
  Aown = Aw_; \
  Mk += mk_ ? pend : 0; \
  int wb_ = __builtin_amdgcn_readfirstlane(__float_as_int(Aw_)); \
  pend = (int)(((unsigned)wb_ >> 23) & 255) - 127; \
  scale_pend = __int_as_float((127 - pend) << 23); \
  if (mk_) gold += rl_f((ECU), tag_); \
}

#define RL(V, U) __builtin_amdgcn_readlane((V), (U))

__launch_bounds__(64)
__attribute__((amdgpu_waves_per_eu(1, 1)))
__global__ void crf_scan(const float* __restrict__ feats,
                         const int* __restrict__ tags,
                         const int* __restrict__ mask,
                         const float* __restrict__ trans,
                         float* __restrict__ out) {
  const int b = blockIdx.x;
  const int lane = threadIdx.x;
  const int g = lane >> 2;   // group 0..15 (owns states 4g..4g+3)
  const int c = lane & 3;    // quad pos == A-quarter index

  __shared__ __align__(16) float Abuf[2][T_];
  __shared__ int tmeta[S_];

  const float LOG2E = 1.4426950408889634f;

  // ---- stage tags+mask into LDS as (tag | mask<<8), coalesced ----
  const int* tagb = tags + (size_t)b * S_;
  const int* mb = mask + (size_t)b * S_;
  #pragma unroll
  for (int t0 = 0; t0 < S_; t0 += 64) {
    int t = t0 + lane;
    tmeta[t] = (tagb[t] & 63) | (mb[t] != 0 ? 256 : 0);
  }

  // ---- E fragments: er2[r][p] = {E[16c+2p][4g+r], E[16c+2p+1][4g+r]} ----
  f32x2 er2[4][8];
  #pragma unroll
  for (int r = 0; r < 4; ++r) {
    #pragma unroll
    for (int p = 0; p < 8; ++p) {
      int i0 = 16 * c + 2 * p;
      int j = 4 * g + r;
      f32x2 e;
      e.x = exp2f(trans[(size_t)i0 * T_ + j] * LOG2E);
      e.y = exp2f(trans[(size_t)(i0 + 1) * T_ + j] * LOG2E);
      er2[r][p] = e;
    }
  }

  // ---- gold: precompute transition term lane-parallel (t = 1..1023) ----
  float gtr = 0.0f;
  #pragma unroll
  for (int u = 0; u < 16; ++u) {
    int t = lane * 16 + u + 1;
    if (t < S_) {
      int m1 = tmeta[t];
      if (m1 & 256) {
        int m0 = tmeta[t - 1];
        gtr += trans[(m0 & 255) * T_ + (m1 & 255)];
      }
    }
  }

  // ---- t = 0 init ----
  const float* fb = feats + (size_t)b * S_ * T_ + lane;
  float e0i = fb[0];                // emit[b,0,lane] == alpha0[lane]
  float A0 = exp2f(e0i * LOG2E);
  Abuf[0][lane] = A0;
  float Aown = A0;
  int Mk = 0;                       // applied exponent sum (exact, uniform)
  int wb0 = __builtin_amdgcn_readfirstlane(__float_as_int(A0));
  int pend = (int)(((unsigned)wb0 >> 23) & 255) - 127;   // lane0 exponent
  float scale_pend = __int_as_float((127 - pend) << 23); // 2^-pend

  int tm0 = __builtin_amdgcn_readfirstlane(tmeta[0]);
  float gold = (tm0 & 256) ? rl_f(e0i, tm0 & 255) : 0.0f;

  // ---- prefetch first chunk of emits (t = 1..8), named scalars only ----
  float epf0 = fb[(size_t)1 * T_], epf1 = fb[(size_t)2 * T_];
  float epf2 = fb[(size_t)3 * T_], epf3 = fb[(size_t)4 * T_];
  float epf4 = fb[(size_t)5 * T_], epf5 = fb[(size_t)6 * T_];
  float epf6 = fb[(size_t)7 * T_], epf7 = fb[(size_t)8 * T_];

  // ---- main scan: 127 chunks of 8 steps (t = 1..1016) ----
  for (int cc = 0; cc < 127; ++cc) {
    const int tbase = 1 + cc * 8;

    float ec0 = epf0, ec1 = epf1, ec2 = epf2, ec3 = epf3;
    float ec4 = epf4, ec5 = epf5, ec6 = epf6, ec7 = epf7;
    float ex0 = exp2f(ec0 * LOG2E), ex1 = exp2f(ec1 * LOG2E);
    float ex2 = exp2f(ec2 * LOG2E), ex3 = exp2f(ec3 * LOG2E);
    float ex4 = exp2f(ec4 * LOG2E), ex5 = exp2f(ec5 * LOG2E);
    float ex6 = exp2f(ec6 * LOG2E), ex7 = exp2f(ec7 * LOG2E);

    // chunk metadata: lanes 0..7 hold tmeta[tbase+0..7]
    int tmv = tmeta[tbase + (lane & 7)];

    // prefetch next chunk (tbase+8 .. tbase+15; only +15 can be OOB)
    {
      const float* fpn = fb + (size_t)(tbase + 8) * T_;
      epf0 = fpn[0 * T_]; epf1 = fpn[1 * T_];
      epf2 = fpn[2 * T_]; epf3 = fpn[3 * T_];
      epf4 = fpn[4 * T_]; epf5 = fpn[5 * T_];
      epf6 = fpn[6 * T_];
      int t7 = tbase + 15;
      epf7 = fb[(size_t)(t7 < S_ ? t7 : S_ - 1) * T_];
    }

    STEPF(0, RL(tmv, 0), ec0, ex0);
    STEPF(1, RL(tmv, 1), ec1, ex1);
    STEPF(0, RL(tmv, 2), ec2, ex2);
    STEPF(1, RL(tmv, 3), ec3, ex3);
    STEPF(0, RL(tmv, 4), ec4, ex4);
    STEPF(1, RL(tmv, 5), ec5, ex5);
    STEPF(0, RL(tmv, 6), ec6, ex6);
    STEPF(1, RL(tmv, 7), ec7, ex7);
  }

  // ---- tail: t = 1017..1023 (7 steps; A is in buffer 0 at entry) ----
  {
    int tt = 1017 + (lane & 7);
    if (tt > 1023) tt = 1023;
    int tmv = tmeta[tt];
    float ex0 = exp2f(epf0 * LOG2E), ex1 = exp2f(epf1 * LOG2E);
    float ex2 = exp2f(epf2 * LOG2E), ex3 = exp2f(epf3 * LOG2E);
    float ex4 = exp2f(epf4 * LOG2E), ex5 = exp2f(epf5 * LOG2E);
    float ex6 = exp2f(epf6 * LOG2E);

    STEPF(0, RL(tmv, 0), epf0, ex0);
    STEPF(1, RL(tmv, 1), epf1, ex1);
    STEPF(0, RL(tmv, 2), epf2, ex2);
    STEPF(1, RL(tmv, 3), epf3, ex3);
    STEPF(0, RL(tmv, 4), epf4, ex4);
    STEPF(1, RL(tmv, 5), epf5, ex5);
    STEPF(0, RL(tmv, 6), epf6, ex6);
  }

  // ---- norm = Mk*ln2 + ln(sum_j W[j]); out = norm - gold ----
  float ssum = Aown;
  float gsum = gtr;
  #pragma unroll
  for (int k = 32; k >= 1; k >>= 1) {
    ssum += __shfl_xor(ssum, k, 64);
    gsum += __shfl_xor(gsum, k, 64);
  }
  double norm = ((double)Mk + (double)log2f(ssum)) * 0.6931471805599453;
  double goldall = (double)gold + (double)gsum;
  if (lane == 0) out[b] = (float)(norm - goldall);
}

extern "C" void kernel_launch(void* const* d_in, const int* in_sizes, int n_in,
                              void* d_out, int out_size, void* d_ws, size_t ws_size,
                              hipStream_t stream) {
  const float* feats = (const float*)d_in[0];
  const int* tags = (const int*)d_in[1];
  const int* mask = (const int*)d_in[2];
  const float* trans = (const float*)d_in[3];
  float* out = (float*)d_out;

  int Bn = in_sizes[0] / (S_ * T_);  // 512
  hipLaunchKernelGGL(crf_scan, dim3(Bn), dim3(64), 0, stream,
                     feats, tags, mask, trans, out);
}